// Round 12
// baseline (58.167 us; speedup 1.0000x reference)
//
#include <hip/hip_runtime.h>

#define NN 10000
#define EE_ 80000
#define NODE_ROWS 20000
#define D2_NODE_BLOCKS 40      // 40*512 = 20480 >= 20000
#define D2_EDGE_BLOCKS 313     // 313*512 = 160256 >= 160000

typedef float f4 __attribute__((ext_vector_type(4)));

// ---------------------------------------------------------------------------
// D1: chunk_kernel — 32 blocks x 256 thr. Block (c,j): augmented product of
// layers 4j..4j+3 (row convention: P = W_{4j} then W_{4j+1} ... ;
// P.W = W_{4j} @ W_{4j+1} @ W_{4j+2} @ W_{4j+3}; bias folds along).
// Output: pt[(c*16+j)*4160]: rows 0..63 = P.W row-major, [4096..4160) = P.b.
// GEMM = R3's proven compose64 (A^T staged stride-68, 4x4 register tiles).
// ---------------------------------------------------------------------------
__global__ __launch_bounds__(256) void chunk_kernel(
    const float* __restrict__ nWhid, const float* __restrict__ nbhid,
    const float* __restrict__ eWhid, const float* __restrict__ ebhid,
    float* __restrict__ pt)
{
  const int t = threadIdx.x;
  const int c = blockIdx.x >> 4;
  const int j = blockIdx.x & 15;
  const float* Wh = c ? eWhid : nWhid;
  const float* bh = c ? ebhid : nbhid;
  const int L0 = 4*j;

  __shared__ float s_at[2][64*68];   // A^T: [k][r], col 64 = A.b[k]
  __shared__ float s_b[65*64];       // B rows + bias row
  __shared__ float s_bp[256];

  // stage A = W_{L0} transposed + bias col
  for (int idx = t; idx < 4160; idx += 256) {
    int r = idx >> 6, k = idx & 63;
    s_at[0][k*68 + r] = (r < 64) ? Wh[(size_t)L0*4096 + idx] : bh[L0*64 + k];
  }
  int cur = 0;
  #pragma unroll 1
  for (int s = 1; s <= 3; ++s) {
    const float* WB = Wh + (size_t)(L0 + s)*4096;
    const float* bB = bh + (size_t)(L0 + s)*64;
    #pragma unroll
    for (int i = 0; i < 4; ++i) {
      int i4 = t + i*256;
      *(float4*)&s_b[i4*4] = *(const float4*)&WB[i4*4];
    }
    if (t < 16) *(float4*)&s_b[4096 + t*4] = *(const float4*)&bB[t*4];
    __syncthreads();

    const int ti = t >> 4, tj = t & 15;
    float acc[4][4];
    #pragma unroll
    for (int d = 0; d < 4; ++d)
      #pragma unroll
      for (int e = 0; e < 4; ++e) acc[d][e] = 0.f;
    #pragma unroll 4
    for (int k = 0; k < 64; ++k) {
      float4 a4 = *(const float4*)&s_at[cur][k*68 + 4*ti];
      float4 b4 = *(const float4*)&s_b[k*64 + 4*tj];
      float av[4] = {a4.x, a4.y, a4.z, a4.w};
      float bv[4] = {b4.x, b4.y, b4.z, b4.w};
      #pragma unroll
      for (int d = 0; d < 4; ++d)
        #pragma unroll
        for (int e = 0; e < 4; ++e) acc[d][e] += av[d]*bv[e];
    }
    // bias partials: b' = A.b @ B.W + B.b (k-split over 4 waves)
    {
      int cc = t & 63, kq = t >> 6;
      float p = 0.f;
      #pragma unroll 4
      for (int kk = 0; kk < 16; ++kk) {
        int k = kq*16 + kk;
        p += s_at[cur][k*68 + 64] * s_b[k*64 + cc];
      }
      s_bp[kq*64 + cc] = p;
    }
    __syncthreads();
    if (s < 3) {
      // write D^T into the other A buffer
      #pragma unroll
      for (int d = 0; d < 4; ++d)
        #pragma unroll
        for (int e = 0; e < 4; ++e)
          s_at[cur^1][(4*tj + e)*68 + 4*ti + d] = acc[d][e];
      if (t < 64)
        s_at[cur^1][t*68 + 64] =
            s_bp[t] + s_bp[64+t] + s_bp[128+t] + s_bp[192+t] + s_b[4096+t];
      __syncthreads();
      cur ^= 1;
    } else {
      float* D = pt + (size_t)(c*16 + j)*4160;
      #pragma unroll
      for (int d = 0; d < 4; ++d)
        *(float4*)&D[(4*ti + d)*64 + 4*tj] =
            make_float4(acc[d][0], acc[d][1], acc[d][2], acc[d][3]);
      if (t < 64)
        D[4096 + t] = s_bp[t] + s_bp[64+t] + s_bp[128+t] + s_bp[192+t] + s_b[4096+t];
    }
  }
}

// ---------------------------------------------------------------------------
// apply helper
// ---------------------------------------------------------------------------
template<int NF>
static __device__ __forceinline__ void mlp_apply_store(const float* x, const float* sW,
                                                       float* po)
{
  float a[16];
  #pragma unroll
  for (int q = 0; q < 16; ++q) a[q] = sW[NF*16 + q];   // bias row
  #pragma unroll
  for (int j = 0; j < NF; ++j) {
    const float xv = x[j];
    #pragma unroll
    for (int q = 0; q < 16; ++q) a[q] += xv * sW[j*16 + q];
  }
  float4* d = (float4*)po;
  d[0] = make_float4(a[0],  a[1],  a[2],  a[3]);
  d[1] = make_float4(a[4],  a[5],  a[6],  a[7]);
  d[2] = make_float4(a[8],  a[9],  a[10], a[11]);
  d[3] = make_float4(a[12], a[13], a[14], a[15]);
}

// ---------------------------------------------------------------------------
// D2: fold_apply_kernel — 353 blocks x 512 thr. Each block redundantly folds
// the 16 chunks of ITS chain (V <- P_j.W @ V, j = 15..0, V = 64x16 suffix in
// LDS [q][m]); beta = sum_j P_j.b @ V accumulates lane-separably; then
// Weff = [Win;bin] fold (+beta+bout) into LDS; then applies its 512 rows.
// ---------------------------------------------------------------------------
__global__ __launch_bounds__(512) void fold_apply_kernel(
    const float* __restrict__ nodes, const float* __restrict__ globals_,
    const float* __restrict__ edges, const int* __restrict__ senders,
    const int* __restrict__ receivers,
    const float* __restrict__ nWin, const float* __restrict__ nbin,
    const float* __restrict__ nWout, const float* __restrict__ nbout,
    const float* __restrict__ eWin, const float* __restrict__ ebin,
    const float* __restrict__ eWout, const float* __restrict__ ebout,
    const float* __restrict__ pt, float* __restrict__ out)
{
  const int t = threadIdx.x;
  const bool is_node = (blockIdx.x < D2_NODE_BLOCKS);
  const int din = is_node ? 31 : 7;
  const float* Win  = is_node ? nWin  : eWin;
  const float* bin  = is_node ? nbin  : ebin;
  const float* Wout = is_node ? nWout : eWout;
  const float* bout = is_node ? nbout : ebout;
  const float* PT = pt + (is_node ? 0 : (size_t)16*4160);

  __shared__ float s_V[2][16*68];   // V^T: [q][m], stride 68
  __shared__ float s_p[64*68];      // chunk W rows, granule-swizzled
  __shared__ float s_pb[64];        // chunk bias
  __shared__ float s_red[8*16];     // cross-wave beta partials
  __shared__ float s_beta[16];
  __shared__ float s_w[32*16];      // Weff for apply

  // init V = Wout: s_V[0][q*68 + k] = Wout[k*16 + q]
  #pragma unroll
  for (int i = 0; i < 2; ++i) {
    int idx = t + i*512;
    int k = idx >> 4, q = idx & 15;
    s_V[0][q*68 + k] = Wout[idx];
  }

  const int k  = t >> 3;            // 0..63 (this thread's output row)
  const int qh = t & 7;             // cols 2qh, 2qh+1
  const int q0 = 2*qh;
  float bpart0 = 0.f, bpart1 = 0.f;

  // prefetch chunk 15 into registers (coalesced f4)
  f4 pA = *(const f4*)&PT[(size_t)15*4160 + t*4];
  f4 pB = *(const f4*)&PT[(size_t)15*4160 + 2048 + t*4];
  f4 pC;
  if (t < 16) pC = *(const f4*)&PT[(size_t)15*4160 + 4096 + t*4];

  // staging dest (granule-swizzled: row kk, granule g stored at g' = (g+kk)&15)
  const int skA = t >> 4,      smA = t & 15;
  const int skB = (t >> 4)+32, smB = t & 15;

  int cur = 0;
  #pragma unroll 1
  for (int jj = 0; jj < 16; ++jj) {
    // write staged chunk to LDS
    *(f4*)&s_p[skA*68 + 4*((smA + skA) & 15)] = pA;
    *(f4*)&s_p[skB*68 + 4*((smB + skB) & 15)] = pB;
    if (t < 16) *(f4*)&s_pb[4*t] = pC;
    __syncthreads();
    // prefetch next chunk (j-1)
    if (jj < 15) {
      const float* nx = PT + (size_t)(14 - jj)*4160;
      pA = *(const f4*)&nx[t*4];
      pB = *(const f4*)&nx[2048 + t*4];
      if (t < 16) pC = *(const f4*)&nx[4096 + 4*t];
    }
    // beta: bpart += P.b[k] * V[k][q]  (V here is S_{j+1})
    {
      float pb = s_pb[k];
      bpart0 = __builtin_fmaf(pb, s_V[cur][q0*68 + k],       bpart0);
      bpart1 = __builtin_fmaf(pb, s_V[cur][(q0+1)*68 + k],   bpart1);
    }
    // V'[k][q] = sum_m P.W[k][m] * V[m][q]
    float acc0 = 0.f, acc1 = 0.f;
    #pragma unroll
    for (int mb = 0; mb < 16; ++mb) {
      f4 w4 = *(const f4*)&s_p[k*68 + 4*((mb + k) & 15)];
      f4 va = *(const f4*)&s_V[cur][q0*68 + 4*mb];
      f4 vb = *(const f4*)&s_V[cur][(q0+1)*68 + 4*mb];
      acc0 = __builtin_fmaf(w4.x, va.x, acc0);
      acc0 = __builtin_fmaf(w4.y, va.y, acc0);
      acc0 = __builtin_fmaf(w4.z, va.z, acc0);
      acc0 = __builtin_fmaf(w4.w, va.w, acc0);
      acc1 = __builtin_fmaf(w4.x, vb.x, acc1);
      acc1 = __builtin_fmaf(w4.y, vb.y, acc1);
      acc1 = __builtin_fmaf(w4.z, vb.z, acc1);
      acc1 = __builtin_fmaf(w4.w, vb.w, acc1);
    }
    const int nxt = cur ^ 1;
    s_V[nxt][q0*68 + k]     = acc0;
    s_V[nxt][(q0+1)*68 + k] = acc1;
    __syncthreads();
    cur = nxt;
  }
  // cur == 0: s_V[0] = S_0 (hidden-chain @ Wout)

  // beta reduce: over k-lanes (stride-8 within wave) then across waves
  {
    #pragma unroll
    for (int off = 8; off < 64; off <<= 1) {
      bpart0 += __shfl_xor(bpart0, off, 64);
      bpart1 += __shfl_xor(bpart1, off, 64);
    }
    int lane = t & 63, wv = t >> 6;
    if (lane < 8) {
      s_red[wv*16 + 2*lane]     = __shfl(bpart0, lane, 64);
      s_red[wv*16 + 2*lane + 1] = __shfl(bpart1, lane, 64);
    }
  }
  __syncthreads();
  if (t < 16) {
    float b = 0.f;
    #pragma unroll
    for (int w = 0; w < 8; ++w) b += s_red[w*16 + t];
    s_beta[t] = b;
  }
  __syncthreads();

  // Weff[r][q] into s_w
  {
    int r = t >> 4, q = t & 15;
    if (r <= din) {
      const float* wr = (r < din) ? (Win + (size_t)r*64) : bin;
      float a0 = 0.f, a1 = 0.f, a2 = 0.f, a3 = 0.f;
      #pragma unroll 4
      for (int kb = 0; kb < 16; ++kb) {
        f4 wv4 = *(const f4*)&wr[kb*4];
        a0 = __builtin_fmaf(wv4.x, s_V[0][q*68 + 4*kb],     a0);
        a1 = __builtin_fmaf(wv4.y, s_V[0][q*68 + 4*kb + 1], a1);
        a2 = __builtin_fmaf(wv4.z, s_V[0][q*68 + 4*kb + 2], a2);
        a3 = __builtin_fmaf(wv4.w, s_V[0][q*68 + 4*kb + 3], a3);
      }
      float acc = (a0 + a1) + (a2 + a3);
      if (r == din) acc += s_beta[q] + bout[q];
      s_w[r*16 + q] = acc;
    }
  }
  __syncthreads();

  // ---------------- apply (512 rows per block) ----------------
  if (is_node) {
    const int rn = blockIdx.x*512 + t;
    if (rn >= NODE_ROWS) return;
    float x[31];
    const float* p = nodes + (size_t)rn*30;
    #pragma unroll
    for (int jf = 0; jf < 15; ++jf) {
      float2 u = *(const float2*)(p + jf*2);
      x[2*jf]     = u.x;
      x[2*jf + 1] = u.y;
    }
    const int b = (rn >= NN) ? 1 : 0;
    x[30] = globals_[b];
    mlp_apply_store<31>(x, s_w, out + (size_t)rn*16);
  } else {
    const int re = (blockIdx.x - D2_NODE_BLOCKS)*512 + t;
    if (re >= 2*EE_) return;
    const int b = (re >= EE_) ? 1 : 0;
    float x[7];
    const float* ep = edges + (size_t)re*3;
    x[0] = ep[0]; x[1] = ep[1]; x[2] = ep[2];
    const int si = senders[re], ri = receivers[re];
    const float* ps = nodes + ((size_t)(b*NN + si))*30;
    const float* pr = nodes + ((size_t)(b*NN + ri))*30;
    const float dx = ps[0] - pr[0];
    const float dy = ps[1] - pr[1];
    const float dz = ps[2] - pr[2];
    x[3] = dx; x[4] = dy; x[5] = dz;
    x[6] = sqrtf(dx*dx + dy*dy + dz*dz);
    mlp_apply_store<7>(x, s_w, out + (size_t)(NODE_ROWS + re)*16);
  }
}

extern "C" void kernel_launch(void* const* d_in, const int* in_sizes, int n_in,
                              void* d_out, int out_size, void* d_ws, size_t ws_size,
                              hipStream_t stream)
{
  const float* nodes    = (const float*)d_in[0];
  const float* globals_ = (const float*)d_in[1];
  const float* edges    = (const float*)d_in[2];
  const int* senders   = (const int*)d_in[3];
  const int* receivers = (const int*)d_in[4];
  const float* nWin  = (const float*)d_in[5];
  const float* nbin  = (const float*)d_in[6];
  const float* nWhid = (const float*)d_in[7];
  const float* nbhid = (const float*)d_in[8];
  const float* nWout = (const float*)d_in[9];
  const float* nbout = (const float*)d_in[10];
  const float* eWin  = (const float*)d_in[11];
  const float* ebin  = (const float*)d_in[12];
  const float* eWhid = (const float*)d_in[13];
  const float* ebhid = (const float*)d_in[14];
  const float* eWout = (const float*)d_in[15];
  const float* ebout = (const float*)d_in[16];
  float* ws  = (float*)d_ws;
  float* out = (float*)d_out;

  chunk_kernel<<<32, 256, 0, stream>>>(nWhid, nbhid, eWhid, ebhid, ws);

  fold_apply_kernel<<<D2_NODE_BLOCKS + D2_EDGE_BLOCKS, 512, 0, stream>>>(
      nodes, globals_, edges, senders, receivers,
      nWin, nbin, nWout, nbout, eWin, ebin, eWout, ebout, ws, out);
}

// Round 13
// 36.887 us; speedup vs baseline: 1.5769x; 1.5769x over previous
//
#include <hip/hip_runtime.h>

#define NN 10000
#define EE_ 80000
#define NODE_ROWS 20000
#define NODE_BLOCKS 79         // ceil(20000/256)
#define EDGE_BLOCKS 625        // 160000/256 exact

typedef float f4 __attribute__((ext_vector_type(4)));

#define GLD4(g, l) __builtin_amdgcn_global_load_lds(                      \
    (const __attribute__((address_space(1))) void*)(g),                   \
    (__attribute__((address_space(3))) void*)(l), 16, 0, 0)
#define GLD1(g, l) __builtin_amdgcn_global_load_lds(                      \
    (const __attribute__((address_space(1))) void*)(g),                   \
    (__attribute__((address_space(3))) void*)(l), 4, 0, 0)

// ---------------------------------------------------------------------------
// D1: chunk_kernel (R12 verbatim, passed) — 32 blocks x 256 thr.
// Block (c,j): augmented product of layers 4j..4j+3.
// Output slot pt[(c*16+j)*4160]: [0..4096) W row-major, [4096..4160) bias.
// ---------------------------------------------------------------------------
__global__ __launch_bounds__(256) void chunk_kernel(
    const float* __restrict__ nWhid, const float* __restrict__ nbhid,
    const float* __restrict__ eWhid, const float* __restrict__ ebhid,
    float* __restrict__ pt)
{
  const int t = threadIdx.x;
  const int c = blockIdx.x >> 4;
  const int j = blockIdx.x & 15;
  const float* Wh = c ? eWhid : nWhid;
  const float* bh = c ? ebhid : nbhid;
  const int L0 = 4*j;

  __shared__ float s_at[2][64*68];   // A^T: [k][r], col 64 = A.b[k]
  __shared__ float s_b[65*64];       // B rows + bias row
  __shared__ float s_bp[256];

  for (int idx = t; idx < 4160; idx += 256) {
    int r = idx >> 6, k = idx & 63;
    s_at[0][k*68 + r] = (r < 64) ? Wh[(size_t)L0*4096 + idx] : bh[L0*64 + k];
  }
  int cur = 0;
  #pragma unroll 1
  for (int s = 1; s <= 3; ++s) {
    const float* WB = Wh + (size_t)(L0 + s)*4096;
    const float* bB = bh + (size_t)(L0 + s)*64;
    #pragma unroll
    for (int i = 0; i < 4; ++i) {
      int i4 = t + i*256;
      *(float4*)&s_b[i4*4] = *(const float4*)&WB[i4*4];
    }
    if (t < 16) *(float4*)&s_b[4096 + t*4] = *(const float4*)&bB[t*4];
    __syncthreads();

    const int ti = t >> 4, tj = t & 15;
    float acc[4][4];
    #pragma unroll
    for (int d = 0; d < 4; ++d)
      #pragma unroll
      for (int e = 0; e < 4; ++e) acc[d][e] = 0.f;
    #pragma unroll 4
    for (int k = 0; k < 64; ++k) {
      float4 a4 = *(const float4*)&s_at[cur][k*68 + 4*ti];
      float4 b4 = *(const float4*)&s_b[k*64 + 4*tj];
      float av[4] = {a4.x, a4.y, a4.z, a4.w};
      float bv[4] = {b4.x, b4.y, b4.z, b4.w};
      #pragma unroll
      for (int d = 0; d < 4; ++d)
        #pragma unroll
        for (int e = 0; e < 4; ++e) acc[d][e] += av[d]*bv[e];
    }
    {
      int cc = t & 63, kq = t >> 6;
      float p = 0.f;
      #pragma unroll 4
      for (int kk = 0; kk < 16; ++kk) {
        int k = kq*16 + kk;
        p += s_at[cur][k*68 + 64] * s_b[k*64 + cc];
      }
      s_bp[kq*64 + cc] = p;
    }
    __syncthreads();
    if (s < 3) {
      #pragma unroll
      for (int d = 0; d < 4; ++d)
        #pragma unroll
        for (int e = 0; e < 4; ++e)
          s_at[cur^1][(4*tj + e)*68 + 4*ti + d] = acc[d][e];
      if (t < 64)
        s_at[cur^1][t*68 + 64] =
            s_bp[t] + s_bp[64+t] + s_bp[128+t] + s_bp[192+t] + s_b[4096+t];
      __syncthreads();
      cur ^= 1;
    } else {
      float* D = pt + (size_t)(c*16 + j)*4160;
      #pragma unroll
      for (int d = 0; d < 4; ++d)
        *(float4*)&D[(4*ti + d)*64 + 4*tj] =
            make_float4(acc[d][0], acc[d][1], acc[d][2], acc[d][3]);
      if (t < 64)
        D[4096 + t] = s_bp[t] + s_bp[64+t] + s_bp[128+t] + s_bp[192+t] + s_b[4096+t];
    }
  }
}

// ---------------------------------------------------------------------------
// D2: fold16_kernel (R11 chain_kernel, passed, with 16 chunk-steps instead of
// 64 layer-steps). 32 blocks x 256 thr (4 waves). Block (c,q): column q of
// chain c. Wave w owns k-slice [16w,16w+16); v via readlane SGPRs; chunks
// staged 2-deep into 3 LDS buffers via global_load_lds, counted vmcnt(10).
// ws: [0..512) node W_eff 32x16, [512..640) edge 8x16.
// ---------------------------------------------------------------------------
__global__ __launch_bounds__(256, 1) void fold16_kernel(
    const float* __restrict__ nWin, const float* __restrict__ nbin,
    const float* __restrict__ nWout, const float* __restrict__ nbout,
    const float* __restrict__ eWin, const float* __restrict__ ebin,
    const float* __restrict__ eWout, const float* __restrict__ ebout,
    const float* __restrict__ pt, float* __restrict__ ws)
{
  const int tid  = threadIdx.x;
  const int lane = tid & 63;
  const int wv   = __builtin_amdgcn_readfirstlane(tid >> 6);  // 0..3
  const int c = blockIdx.x >> 4;         // 0 node, 1 edge
  const int q = blockIdx.x & 15;         // output column
  const float* Win  = c ? eWin  : nWin;
  const float* bin  = c ? ebin  : nbin;
  const float* Wout = c ? eWout : nWout;
  const float* bout = c ? ebout : nbout;
  const float* PT = pt + (size_t)c*16*4160;
  const int din = c ? 7 : 31;
  float* weff = ws + (c ? 512 : 0);

  __shared__ float lds_f[13312];   // 3*4352 buffers + 256 partials = 53 KB

  const int r4 = lane >> 4, c16 = lane & 15;
  const int oE = r4*64 + ((c16 ^ r4) << 2);        // GLD4 slot parity even
  const int oO = r4*64 + ((c16 ^ (4 | r4)) << 2);  // GLD4 slot parity odd
  const int swz = lane & 7;
  const int aw0 = lane*256 + (((4*wv + 0) ^ swz) << 4);
  const int aw1 = lane*256 + (((4*wv + 1) ^ swz) << 4);
  const int aw2 = lane*256 + (((4*wv + 2) ^ swz) << 4);
  const int aw3 = lane*256 + (((4*wv + 3) ^ swz) << 4);
  const int ab  = 16384 + wv*256 + lane*4;          // bias copy (per-wave)
  const int apw = 52224 + lane*16 + wv*4;           // partial write
  const int apr = 52224 + lane*16;                  // partial read (b128)

  float vlane = Wout[lane*16 + q];                  // V_16 column = Wout[:,q]
  float bpart = 0.f;
  const int kbase = 16*wv;
  float s[16];
  #pragma unroll
  for (int j = 0; j < 16; ++j)
    s[j] = __uint_as_float(__builtin_amdgcn_readlane(__float_as_uint(vlane), kbase + j));

#define STAGE(BF, L) do {                                                 \
    const float* gW_ = PT + (size_t)(L)*4160 + wv*1024;                   \
    float* lW_ = lds_f + (BF)*4352 + wv*1024;                             \
    GLD4(gW_ +   0 + oE, lW_ +   0);                                      \
    GLD4(gW_ + 256 + oO, lW_ + 256);                                      \
    GLD4(gW_ + 512 + oE, lW_ + 512);                                      \
    GLD4(gW_ + 768 + oO, lW_ + 768);                                      \
    GLD1(PT + (size_t)(L)*4160 + 4096 + lane,                             \
         lds_f + (BF)*4352 + 4096 + wv*64);                               \
  } while (0)

#define CSTEP(OFS, VMC, STAGESTMT) do {                                   \
    STAGESTMT;                                                            \
    asm volatile("s_waitcnt vmcnt(" #VMC ") lgkmcnt(0)" ::: "memory");    \
    __builtin_amdgcn_s_barrier();        /* this step's buffer ready */   \
    f4 f0_, f1_, f2_, f3_; float bb_;                                     \
    asm volatile("ds_read_b128 %0, %5 offset:" #OFS "\n\t"                \
                 "ds_read_b128 %1, %6 offset:" #OFS "\n\t"                \
                 "ds_read_b128 %2, %7 offset:" #OFS "\n\t"                \
                 "ds_read_b128 %3, %8 offset:" #OFS "\n\t"                \
                 "ds_read_b32  %4, %9 offset:" #OFS "\n\t"                \
                 "s_waitcnt lgkmcnt(0)"                                   \
                 : "=&v"(f0_), "=&v"(f1_), "=&v"(f2_), "=&v"(f3_), "=&v"(bb_) \
                 : "v"(aw0), "v"(aw1), "v"(aw2), "v"(aw3), "v"(ab)        \
                 : "memory");                                             \
    __builtin_amdgcn_sched_barrier(0);                                    \
    bpart = __builtin_fmaf(bb_, vlane, bpart);                            \
    float a0_ = __builtin_fmaf(f0_.y, s[1],  f0_.x * s[0]);               \
    a0_ = __builtin_fmaf(f0_.z, s[2],  a0_);                              \
    a0_ = __builtin_fmaf(f0_.w, s[3],  a0_);                              \
    float a1_ = __builtin_fmaf(f1_.y, s[5],  f1_.x * s[4]);               \
    a1_ = __builtin_fmaf(f1_.z, s[6],  a1_);                              \
    a1_ = __builtin_fmaf(f1_.w, s[7],  a1_);                              \
    float a2_ = __builtin_fmaf(f2_.y, s[9],  f2_.x * s[8]);               \
    a2_ = __builtin_fmaf(f2_.z, s[10], a2_);                              \
    a2_ = __builtin_fmaf(f2_.w, s[11], a2_);                              \
    float a3_ = __builtin_fmaf(f3_.y, s[13], f3_.x * s[12]);              \
    a3_ = __builtin_fmaf(f3_.z, s[14], a3_);                              \
    a3_ = __builtin_fmaf(f3_.w, s[15], a3_);                              \
    float acc_ = (a0_ + a1_) + (a2_ + a3_);                               \
    asm volatile("ds_write_b32 %0, %1\n\t"                                \
                 "s_waitcnt lgkmcnt(0)"                                   \
                 :: "v"(apw), "v"(acc_) : "memory");                      \
    __builtin_amdgcn_s_barrier();        /* partials visible */           \
    f4 p4_;                                                               \
    asm volatile("ds_read_b128 %0, %1\n\t"                                \
                 "s_waitcnt lgkmcnt(0)"                                   \
                 : "=&v"(p4_) : "v"(apr) : "memory");                     \
    __builtin_amdgcn_sched_barrier(0);                                    \
    vlane = (p4_.x + p4_.y) + (p4_.z + p4_.w);                            \
    _Pragma("unroll")                                                     \
    for (int jj = 0; jj < 16; ++jj)                                       \
      s[jj] = __uint_as_float(__builtin_amdgcn_readlane(                  \
                  __float_as_uint(vlane), kbase + jj));                   \
  } while (0)

  // prologue: prime buffers 0 (chunk 15) and 1 (chunk 14) -> 10 outstanding
  STAGE(0, 15);
  STAGE(1, 14);

  int L = 15;
  #pragma unroll 1
  for (int ii = 0; ii < 4; ++ii) {       // chunks 15..4
    CSTEP(0,     10, STAGE(2, L-2));
    CSTEP(17408, 10, STAGE(0, L-3));
    CSTEP(34816, 10, STAGE(1, L-4));
    L -= 3;
  }
  // tail: chunks 3,2,1,0
  CSTEP(0,     10, STAGE(2, 1));
  CSTEP(17408, 10, STAGE(0, 0));
  CSTEP(34816, 5,  (void)0);
  CSTEP(0,     0,  (void)0);
#undef CSTEP
#undef STAGE
  // vlane == V_0[lane]; bpart = lane's share of beta (identical in all waves)

  if (wv != 0) return;                   // no barriers below

  float red = __builtin_fmaf(bin[lane], vlane, bpart);
  #pragma unroll
  for (int off = 32; off > 0; off >>= 1) red += __shfl_xor(red, off, 64);

  float* sv = lds_f;                     // buffers dead; share v0 wave-locally
  sv[lane] = vlane;
  __builtin_amdgcn_sched_barrier(0);

  if (lane == din) {
    weff[din*16 + q] = red + bout[q];
  } else if (lane < din) {
    float a0 = 0.f, a1 = 0.f, a2 = 0.f, a3 = 0.f;
    const float* wr = Win + (size_t)lane*64;
    #pragma unroll
    for (int kb = 0; kb < 16; ++kb) {
      f4 vv = *(const f4*)&sv[kb*4];
      f4 wv4 = *(const f4*)&wr[kb*4];
      a0 = __builtin_fmaf(wv4.x, vv.x, a0);
      a1 = __builtin_fmaf(wv4.y, vv.y, a1);
      a2 = __builtin_fmaf(wv4.z, vv.z, a2);
      a3 = __builtin_fmaf(wv4.w, vv.w, a3);
    }
    weff[lane*16 + q] = (a0 + a1) + (a2 + a3);
  }
}

// ---------------------------------------------------------------------------
// D3: apply (validated R3..R11, ~2.3 µs)
// ---------------------------------------------------------------------------
template<int NF>
static __device__ __forceinline__ void mlp_apply_store(const float* x, const float* sW,
                                                       float* po)
{
  float a[16];
  #pragma unroll
  for (int q = 0; q < 16; ++q) a[q] = sW[NF*16 + q];   // bias row
  #pragma unroll
  for (int j = 0; j < NF; ++j) {
    const float xv = x[j];
    #pragma unroll
    for (int q = 0; q < 16; ++q) a[q] += xv * sW[j*16 + q];
  }
  float4* d = (float4*)po;
  d[0] = make_float4(a[0],  a[1],  a[2],  a[3]);
  d[1] = make_float4(a[4],  a[5],  a[6],  a[7]);
  d[2] = make_float4(a[8],  a[9],  a[10], a[11]);
  d[3] = make_float4(a[12], a[13], a[14], a[15]);
}

__global__ __launch_bounds__(256) void apply_kernel(
    const float* __restrict__ nodes, const float* __restrict__ globals_,
    const float* __restrict__ edges, const int* __restrict__ senders,
    const int* __restrict__ receivers, const float* __restrict__ ws,
    float* __restrict__ out)
{
  __shared__ float sW[32*16];
  const bool is_node = (blockIdx.x < NODE_BLOCKS);
  {
    const float* src = is_node ? ws : ws + 512;
    const int n = is_node ? 32*16 : 8*16;
    for (int j = threadIdx.x; j < n; j += 256) sW[j] = src[j];
  }
  __syncthreads();

  if (is_node) {
    const int rn = blockIdx.x*256 + threadIdx.x;
    if (rn >= NODE_ROWS) return;
    float x[31];
    const float* p = nodes + (size_t)rn*30;
    #pragma unroll
    for (int j = 0; j < 15; ++j) {
      float2 u = *(const float2*)(p + j*2);
      x[2*j]     = u.x;
      x[2*j + 1] = u.y;
    }
    const int b = (rn >= NN) ? 1 : 0;
    x[30] = globals_[b];
    mlp_apply_store<31>(x, sW, out + (size_t)rn*16);
  } else {
    const int re = (blockIdx.x - NODE_BLOCKS)*256 + threadIdx.x;  // < 160000 exact
    const int b = (re >= EE_) ? 1 : 0;
    float x[7];
    const float* ep = edges + (size_t)re*3;
    x[0] = ep[0]; x[1] = ep[1]; x[2] = ep[2];
    const int si = senders[re], ri = receivers[re];
    const float* ps = nodes + ((size_t)(b*NN + si))*30;
    const float* pr = nodes + ((size_t)(b*NN + ri))*30;
    const float dx = ps[0] - pr[0];
    const float dy = ps[1] - pr[1];
    const float dz = ps[2] - pr[2];
    x[3] = dx; x[4] = dy; x[5] = dz;
    x[6] = sqrtf(dx*dx + dy*dy + dz*dz);
    mlp_apply_store<7>(x, sW, out + (size_t)(NODE_ROWS + re)*16);
  }
}

extern "C" void kernel_launch(void* const* d_in, const int* in_sizes, int n_in,
                              void* d_out, int out_size, void* d_ws, size_t ws_size,
                              hipStream_t stream)
{
  const float* nodes    = (const float*)d_in[0];
  const float* globals_ = (const float*)d_in[1];
  const float* edges    = (const float*)d_in[2];
  const int* senders   = (const int*)d_in[3];
  const int* receivers = (const int*)d_in[4];
  const float* nWin  = (const float*)d_in[5];
  const float* nbin  = (const float*)d_in[6];
  const float* nWhid = (const float*)d_in[7];
  const float* nbhid = (const float*)d_in[8];
  const float* nWout = (const float*)d_in[9];
  const float* nbout = (const float*)d_in[10];
  const float* eWin  = (const float*)d_in[11];
  const float* ebin  = (const float*)d_in[12];
  const float* eWhid = (const float*)d_in[13];
  const float* ebhid = (const float*)d_in[14];
  const float* eWout = (const float*)d_in[15];
  const float* ebout = (const float*)d_in[16];
  float* ws  = (float*)d_ws;
  float* out = (float*)d_out;
  float* pt  = ws + 1024;               // 32 slots x 4160 f

  chunk_kernel<<<32, 256, 0, stream>>>(nWhid, nbhid, eWhid, ebhid, pt);

  fold16_kernel<<<32, 256, 0, stream>>>(
      nWin, nbin, nWout, nbout, eWin, ebin, eWout, ebout, pt, ws);

  apply_kernel<<<NODE_BLOCKS + EDGE_BLOCKS, 256, 0, stream>>>(
      nodes, globals_, edges, senders, receivers, ws, out);
}